// Round 7
// baseline (689.559 us; speedup 1.0000x reference)
//
#include <hip/hip_runtime.h>
#include <hip/hip_bf16.h>

// Problem constants (match reference)
#define D_MODEL 1024
#define N_HEADS 16
#define HEAD_DIM 64
#define SEQ_T 2048
#define BATCH 4

#define SL2E 0.18033688011f   // 0.125 * log2(e), baked into Q at GEMM epilogue

typedef short s8v  __attribute__((ext_vector_type(8)));   // 8 x bf16 bits
typedef float f32x4 __attribute__((ext_vector_type(4)));
typedef unsigned long long ull;

static __device__ __forceinline__ unsigned short f2bf(float f) {
  union { float f; unsigned int u; } v; v.f = f;
  unsigned int u = v.u;
  return (unsigned short)((u + 0x7FFF + ((u >> 16) & 1)) >> 16);  // RNE
}

// pack 2 f32 -> 2 bf16 in one instr (RNE); no builtin on gfx950, inline asm
static __device__ __forceinline__ unsigned int cvtpk_bf16(float lo, float hi) {
  unsigned int r;
  asm("v_cvt_pk_bf16_f32 %0, %1, %2" : "=v"(r) : "v"(lo), "v"(hi));
  return r;
}

#if __has_builtin(__builtin_amdgcn_exp2f)
#define EXP2(x) __builtin_amdgcn_exp2f(x)
#else
#define EXP2(x) exp2f(x)
#endif

// async global->LDS, 16B per lane; LDS dest = wave-uniform base + lane*16
static __device__ __forceinline__ void glds16(const void* g, void* l) {
  __builtin_amdgcn_global_load_lds(
      (const __attribute__((address_space(1))) void*)g,
      (__attribute__((address_space(3))) void*)l, 16, 0, 0);
}

// ---------------------------------------------------------------------------
// bf16 MFMA GEMM (m97 structure, proven 67-72.6 µs QKV): C = A @ B + bias
//   MODE 0: fp32 out. MODE 1: QKV split — Q cols (<1024) pre-scaled by SL2E
//   into qkb; K cols (1024..2047) into qkb; V cols -> vT [bh][d][T] b64-packed.
// ---------------------------------------------------------------------------
template<int MODE>
__global__ __launch_bounds__(256) void gemm_bt_kernel(
    const unsigned short* __restrict__ A, const unsigned short* __restrict__ Bt,
    const float* __restrict__ bias, float* __restrict__ Cout,
    unsigned short* __restrict__ qkb, unsigned short* __restrict__ vT,
    int M, int N, int K)
{
  __shared__ unsigned short Al[128 * 64];
  __shared__ unsigned short Bl[128 * 64];

  const int tid  = threadIdx.x;
  const int lane = tid & 63;
  const int wave = tid >> 6;
  const int col  = lane & 15;
  const int quad = lane >> 4;
  const int wm   = (wave & 1) * 64;
  const int wn   = (wave >> 1) * 64;
  const int bm0  = blockIdx.y * 128;
  const int bn0  = blockIdx.x * 128;
  const int cx   = col & 7;

  f32x4 acc[4][4];
  #pragma unroll
  for (int t = 0; t < 4; ++t)
    #pragma unroll
    for (int u = 0; u < 4; ++u) acc[t][u] = (f32x4)0.f;

  for (int k0 = 0; k0 < K; k0 += 64) {
    __syncthreads();
    #pragma unroll
    for (int i = 0; i < 4; ++i) {
      int idx = i * 256 + tid;
      int row = idx >> 3;
      int gc  = (idx & 7) ^ (row & 7);
      glds16(A  + (size_t)(bm0 + row) * K + k0 + gc * 8, &Al[idx * 8]);
      glds16(Bt + (size_t)(bn0 + row) * K + k0 + gc * 8, &Bl[idx * 8]);
    }
    __syncthreads();

    #pragma unroll
    for (int s = 0; s < 2; ++s) {
      s8v af[4], bf[4];
      #pragma unroll
      for (int t = 0; t < 4; ++t) {
        int ar = wm + t * 16 + col;
        af[t] = *(const s8v*)&Al[ar * 64 + (((s * 4 + quad) ^ cx) * 8)];
        int br = wn + t * 16 + col;
        bf[t] = *(const s8v*)&Bl[br * 64 + (((s * 4 + quad) ^ cx) * 8)];
      }
      #pragma unroll
      for (int t = 0; t < 4; ++t)
        #pragma unroll
        for (int u = 0; u < 4; ++u)
          acc[t][u] = __builtin_amdgcn_mfma_f32_16x16x32_bf16(
              af[t], bf[u], acc[t][u], 0, 0, 0);
    }
  }

  float bv[4];
  #pragma unroll
  for (int u = 0; u < 4; ++u) bv[u] = bias[bn0 + wn + u * 16 + col];

  if (MODE == 1 && bn0 >= 2048) {
    // V epilogue: packed b64 stores into vT [bh][d][T]
    #pragma unroll
    for (int t = 0; t < 4; ++t) {
      int m_base = bm0 + wm + t * 16 + quad * 4;
      #pragma unroll
      for (int u = 0; u < 4; ++u) {
        int hd = (bn0 + wn + u * 16 + col) - 2048;       // h*64 + d
        size_t bh = (size_t)(bm0 >> 11) * 16 + (hd >> 6);
        ull pk = (ull)f2bf(acc[t][u][0] + bv[u])
               | ((ull)f2bf(acc[t][u][1] + bv[u]) << 16)
               | ((ull)f2bf(acc[t][u][2] + bv[u]) << 32)
               | ((ull)f2bf(acc[t][u][3] + bv[u]) << 48);
        *(ull*)(vT + (bh * 64 + (hd & 63)) * 2048 + (m_base & 2047)) = pk;
      }
    }
  } else {
    const float sc = (MODE == 1 && (bn0 + wn) < 1024) ? SL2E : 1.0f;  // Q pre-scale
    #pragma unroll
    for (int t = 0; t < 4; ++t) {
      #pragma unroll
      for (int r = 0; r < 4; ++r) {
        size_t m = bm0 + wm + t * 16 + quad * 4 + r;
        #pragma unroll
        for (int u = 0; u < 4; ++u) {
          int n = bn0 + wn + u * 16 + col;
          float v = acc[t][u][r] + bv[u];
          if (MODE == 0) Cout[m * N + n] = v;
          else           qkb[m * 2048 + n] = f2bf(v * sc);
        }
      }
    }
  }
}

// ---------------------------------------------------------------------------
// Merged prep: x cast (blocks 0..8191), W_qkv transpose (8192..11263),
// W_proj transpose (11264..12287).
// ---------------------------------------------------------------------------
static __device__ __forceinline__ void transpose_tile(
    const float* __restrict__ W, unsigned short* __restrict__ Wt,
    int K, int N, int n0, int k0)
{
  __shared__ float tile[32][33];
  const int tx = threadIdx.x & 31, ty = threadIdx.x >> 5;
  #pragma unroll
  for (int i = 0; i < 4; ++i)
    tile[ty + i * 8][tx] = W[(size_t)(k0 + ty + i * 8) * N + n0 + tx];
  __syncthreads();
  #pragma unroll
  for (int i = 0; i < 4; ++i)
    Wt[(size_t)(n0 + ty + i * 8) * K + k0 + tx] = f2bf(tile[tx][ty + i * 8]);
}

__global__ __launch_bounds__(256) void prep_kernel(
    const float* __restrict__ x, const float* __restrict__ W_qkv,
    const float* __restrict__ W_proj, ushort4* __restrict__ xb,
    unsigned short* __restrict__ wqt, unsigned short* __restrict__ wpt)
{
  const int bid = blockIdx.x;
  if (bid < 8192) {
    int i = bid * 256 + threadIdx.x;
    float4 v = ((const float4*)x)[i];
    ushort4 o;
    o.x = f2bf(v.x); o.y = f2bf(v.y); o.z = f2bf(v.z); o.w = f2bf(v.w);
    xb[i] = o;
  } else if (bid < 8192 + 3072) {
    int b2 = bid - 8192;                      // W_qkv [1024, 3072] -> wqt
    transpose_tile(W_qkv, wqt, 1024, 3072, (b2 % 96) * 32, (b2 / 96) * 32);
  } else {
    int b3 = bid - 11264;                     // W_proj [1024, 1024] -> wpt
    transpose_tile(W_proj, wpt, 1024, 1024, (b3 % 32) * 32, (b3 / 32) * 32);
  }
}

// ---------------------------------------------------------------------------
// bf16 MFMA flash causal attention — QT=256, 8 waves (512 thr), async dbuf,
// fixed-max softmax, TRANSPOSED-S + k-interleaved K-row permutation
// (round-5 proven; P never touches LDS).
// This round: KT 64 -> 128 ([buf][half] subtiles; per-64-subtile stage/read
// code byte-identical) => __syncthreads cadence HALVES on the critical-path
// block (32 -> 16 barriers at qblk=7), each prefetch hides under 2x body.
// Plus T5 setprio(1) around the QK and PV MFMA clusters (m191: attn-positive).
// ---------------------------------------------------------------------------
__global__ __launch_bounds__(512, 4) void attn_mfma_kernel(
    const unsigned short* __restrict__ qk, const unsigned short* __restrict__ vT,
    unsigned short* __restrict__ y)
{
  __shared__ unsigned short Ks[2][2][64 * 64];   // [buf][half] 32 KB
  __shared__ unsigned short Vs[2][2][64 * 64];   // [buf][half] 32 KB

  const int tid  = threadIdx.x;
  const int wave = tid >> 6;
  const int lane = tid & 63;
  const int col  = lane & 15;
  const int quad = lane >> 4;
  const int cx   = col & 7;

  const int bh = blockIdx.x;
  const int b = bh >> 4, h = bh & 15;
  // pair-balanced qblk order: y=0..3 -> 7,6,5,4 (dispatched first), y=4..7 -> 0,1,2,3
  const int yy = (int)blockIdx.y;
  const int qblk = (yy < 4) ? (7 - yy) : (yy - 4);
  const int q0 = qblk * 256;
  const int nt = 2 * qblk + 2;               // 128-k tiles (even, >= 2)
  const int C2 = 2048;

  const unsigned short* qbase = qk + (size_t)b * SEQ_T * C2 + h * 64;
  const unsigned short* kbase = qbase + 1024;
  const unsigned short* vbase = vT + (size_t)bh * 64 * 2048;

  // Q fragments for both stripes (B-operand: rows of Q, pre-scaled by SL2E)
  s8v qf[2][2];
  #pragma unroll
  for (int s = 0; s < 2; ++s)
    #pragma unroll
    for (int c = 0; c < 2; ++c)
      qf[s][c] = *(const s8v*)(qbase +
          (size_t)(q0 + s * 128 + wave * 16 + col) * C2 + c * 32 + quad * 8);

  f32x4 acc[2][4];
  #pragma unroll
  for (int s = 0; s < 2; ++s)
    #pragma unroll
    for (int t = 0; t < 4; ++t) acc[s][t] = (f32x4)0.f;
  float lsum[2] = {0.f, 0.f};                // per-lane partial row sum, q=col

  // stage one 128-k tile = two 64-k subtiles; per-subtile pattern identical
  // to the proven KT=64 stage (dest = uniform + lane*16).
  // K uses sigma(row) = (row&7)^((row>>1)&4); V keeps (row&7)
  auto stage = [&](int t128, int bi) {
    #pragma unroll
    for (int hh = 0; hh < 2; ++hh) {
      const int k0 = t128 * 128 + hh * 64;
      int row = tid >> 3;
      int gk  = (tid & 7) ^ (row & 7) ^ ((row >> 1) & 4);
      int gv  = (tid & 7) ^ (row & 7);
      glds16(kbase + (size_t)(k0 + row) * C2 + gk * 8, &Ks[bi][hh][tid * 8]);
      glds16(vbase + (size_t)row * 2048 + k0 + gv * 8, &Vs[bi][hh][tid * 8]);
    }
  };

  auto sub_body = [&](int k0, const unsigned short* Kl, const unsigned short* Vl) {
    // K fragments, k-interleaved row permutation (A-operand)
    s8v kf[4][2];
    const int pbase = (col >> 2) * 8 + (col & 3);
    #pragma unroll
    for (int t = 0; t < 4; ++t) {
      const int rowt = pbase + (t & 1) * 4 + (t >> 1) * 32;
      const int sx   = (rowt & 7) ^ ((rowt >> 1) & 4);
      #pragma unroll
      for (int c = 0; c < 2; ++c)
        kf[t][c] = *(const s8v*)&Kl[rowt * 64 + (((c * 4 + quad) ^ sx) * 8)];
    }

    // pass 1: QK^T + softmax per stripe; P stays in registers (pf)
    s8v pf[2][2];
    bool live[2];
    #pragma unroll
    for (int s = 0; s < 2; ++s) {
      const int qs = q0 + s * 128 + wave * 16;
      live[s] = (k0 <= qs + 15);
      if (!live[s]) continue;

      f32x4 st[4];
      #pragma unroll
      for (int t = 0; t < 4; ++t) st[t] = (f32x4)0.f;
      __builtin_amdgcn_s_setprio(1);
      #pragma unroll
      for (int t = 0; t < 4; ++t)
        #pragma unroll
        for (int c = 0; c < 2; ++c)
          st[t] = __builtin_amdgcn_mfma_f32_16x16x32_bf16(kf[t][c], qf[s][c], st[t], 0, 0, 0);
      __builtin_amdgcn_s_setprio(0);

      // lane (col,quad) holds P[q=qs+col][k0 + 8*quad + r + 4*(t&1) + 32*(t>>1)]
      uint2 pw[4];
      const bool diag = (k0 + 63 > qs);       // wave-uniform
      if (!diag) {
        #pragma unroll
        for (int t = 0; t < 4; ++t) {
          float e0 = EXP2(st[t][0]);
          float e1 = EXP2(st[t][1]);
          float e2 = EXP2(st[t][2]);
          float e3 = EXP2(st[t][3]);
          lsum[s] += (e0 + e1) + (e2 + e3);
          pw[t].x = cvtpk_bf16(e0, e1);
          pw[t].y = cvtpk_bf16(e2, e3);
        }
      } else {
        const int qg = qs + col;
        #pragma unroll
        for (int t = 0; t < 4; ++t) {
          const int kt0 = k0 + 4 * (t & 1) + 32 * (t >> 1);
          if (kt0 > qs + 15) {                // chunk fully masked (uniform)
            pw[t].x = 0u; pw[t].y = 0u;
          } else {
            const int kq = kt0 + 8 * quad;
            float e[4];
            #pragma unroll
            for (int r = 0; r < 4; ++r) {
              float v = EXP2(st[t][r]);
              if (kq + r > qg) v = 0.f;
              e[r] = v;
            }
            lsum[s] += (e[0] + e[1]) + (e[2] + e[3]);
            pw[t].x = cvtpk_bf16(e[0], e[1]);
            pw[t].y = cvtpk_bf16(e[2], e[3]);
          }
        }
      }
      // pf[c] = P chunk k = c*32 + quad*8 + {0..7}  (all lane-local)
      #pragma unroll
      for (int c = 0; c < 2; ++c) {
        union { uint4 u; s8v v; } cc;
        cc.u.x = pw[2 * c].x;  cc.u.y = pw[2 * c].y;
        cc.u.z = pw[2 * c + 1].x;  cc.u.w = pw[2 * c + 1].y;
        pf[s][c] = cc.v;
      }
    }

    // pass 2: V^T fragments (B-operand, rows d = t*16+col), then O += P·V^T
    s8v vf[4][2];
    #pragma unroll
    for (int t = 0; t < 4; ++t)
      #pragma unroll
      for (int c = 0; c < 2; ++c)
        vf[t][c] = *(const s8v*)&Vl[(t * 16 + col) * 64 + (((c * 4 + quad) ^ cx) * 8)];
    __builtin_amdgcn_s_setprio(1);
    #pragma unroll
    for (int s = 0; s < 2; ++s) {
      if (!live[s]) continue;
      #pragma unroll
      for (int t = 0; t < 4; ++t)
        #pragma unroll
        for (int c = 0; c < 2; ++c)
          acc[s][t] = __builtin_amdgcn_mfma_f32_16x16x32_bf16(pf[s][c], vf[t][c], acc[s][t], 0, 0, 0);
    }
    __builtin_amdgcn_s_setprio(0);
  };

  auto body = [&](int t128, int bi) {
    sub_body(t128 * 128,      &Ks[bi][0][0], &Vs[bi][0][0]);
    sub_body(t128 * 128 + 64, &Ks[bi][1][0], &Vs[bi][1][0]);
  };

  stage(0, 0);
  for (int t = 0; t < nt; t += 2) {
    __syncthreads();                               // buf0 staged & visible
    if (t + 1 < nt) stage(t + 1, 1);               // prefetch overlaps compute
    body(t, 0);
    if (t + 1 < nt) {
      __syncthreads();                             // buf1 staged & visible
      if (t + 2 < nt) stage(t + 2, 0);
      body(t + 1, 1);
    }
  }

  // epilogue: reduce row sums across quads, broadcast per q, write y (bf16)
  #pragma unroll
  for (int s = 0; s < 2; ++s) {
    float v = lsum[s];
    v += __shfl_xor(v, 16);
    v += __shfl_xor(v, 32);                        // full sum for q = qs+col
    #pragma unroll
    for (int r = 0; r < 4; ++r) {
      float inv = 1.0f / __shfl(v, quad * 4 + r);  // sum for q-local quad*4+r
      int q = q0 + s * 128 + wave * 16 + quad * 4 + r;
      unsigned short* yrow = y + (size_t)(b * SEQ_T + q) * D_MODEL + h * 64;
      #pragma unroll
      for (int t = 0; t < 4; ++t)
        yrow[t * 16 + col] = f2bf(acc[s][t][r] * inv);
    }
  }
}

// ---------------------------------------------------------------------------
extern "C" void kernel_launch(void* const* d_in, const int* in_sizes, int n_in,
                              void* d_out, int out_size, void* d_ws, size_t ws_size,
                              hipStream_t stream) {
  const float* x      = (const float*)d_in[0];
  const float* W_qkv  = (const float*)d_in[1];
  const float* b_qkv  = (const float*)d_in[2];
  const float* W_proj = (const float*)d_in[3];
  const float* b_proj = (const float*)d_in[4];
  float* out = (float*)d_out;

  const int M  = BATCH * SEQ_T;    // 8192
  const int C  = D_MODEL;          // 1024
  const int C3 = 3 * D_MODEL;      // 3072

  // workspace (bf16 = unsigned short), total ~88 MB
  unsigned short* xb  = (unsigned short*)d_ws;           // [M, C]      16 MB
  unsigned short* wqt = xb  + (size_t)M * C;             // [3C, C]      6 MB
  unsigned short* wpt = wqt + (size_t)C3 * C;            // [C, C]       2 MB
  unsigned short* qkb = wpt + (size_t)C * C;             // [M, 2C]     32 MB
  unsigned short* vTb = qkb + (size_t)M * 2 * C;         // [64,64,T]   16 MB
  unsigned short* yb  = vTb + (size_t)64 * 64 * SEQ_T;   // [M, C]      16 MB

  dim3 blk(256);

  // 0) merged prep: cast x, transpose-cast both weights
  prep_kernel<<<dim3(8192 + 3072 + 1024), blk, 0, stream>>>(
      x, W_qkv, W_proj, (ushort4*)xb, wqt, wpt);

  // 1) qkv GEMM: Q (pre-scaled), K -> qkb; V -> vTb transposed [bh][d][T]
  gemm_bt_kernel<1><<<dim3(C3 / 128, M / 128), blk, 0, stream>>>(
      xb, wqt, b_qkv, nullptr, qkb, vTb, M, C3, C);

  // 2) causal flash attention: QT=256, KT=128, 512 thr, P in registers
  attn_mfma_kernel<<<dim3(BATCH * N_HEADS, SEQ_T / 256), dim3(512), 0, stream>>>(
      qkb, vTb, yb);

  // 3) out = y @ W_proj + b_proj (fp32)
  gemm_bt_kernel<0><<<dim3(C / 128, M / 128), blk, 0, stream>>>(
      yb, wpt, b_proj, out, nullptr, nullptr, M, C, C);
}

// Round 8
// 240.658 us; speedup vs baseline: 2.8653x; 2.8653x over previous
//
#include <hip/hip_runtime.h>
#include <hip/hip_bf16.h>

// Problem constants (match reference)
#define D_MODEL 1024
#define N_HEADS 16
#define HEAD_DIM 64
#define SEQ_T 2048
#define BATCH 4

#define SL2E 0.18033688011f   // 0.125 * log2(e), baked into Q at GEMM epilogue

typedef short s8v  __attribute__((ext_vector_type(8)));   // 8 x bf16 bits
typedef float f32x4 __attribute__((ext_vector_type(4)));
typedef unsigned long long ull;

static __device__ __forceinline__ unsigned short f2bf(float f) {
  union { float f; unsigned int u; } v; v.f = f;
  unsigned int u = v.u;
  return (unsigned short)((u + 0x7FFF + ((u >> 16) & 1)) >> 16);  // RNE
}

// pack 2 f32 -> 2 bf16 in one instr (RNE); no builtin on gfx950, inline asm
static __device__ __forceinline__ unsigned int cvtpk_bf16(float lo, float hi) {
  unsigned int r;
  asm("v_cvt_pk_bf16_f32 %0, %1, %2" : "=v"(r) : "v"(lo), "v"(hi));
  return r;
}

#if __has_builtin(__builtin_amdgcn_exp2f)
#define EXP2(x) __builtin_amdgcn_exp2f(x)
#else
#define EXP2(x) exp2f(x)
#endif

// async global->LDS, 16B per lane; LDS dest = wave-uniform base + lane*16
static __device__ __forceinline__ void glds16(const void* g, void* l) {
  __builtin_amdgcn_global_load_lds(
      (const __attribute__((address_space(1))) void*)g,
      (__attribute__((address_space(3))) void*)l, 16, 0, 0);
}

// ---------------------------------------------------------------------------
// bf16 MFMA GEMM (m97 structure, proven 67-72.6 µs QKV): C = A @ B + bias
//   MODE 0: fp32 out. MODE 1: QKV split — Q cols (<1024) pre-scaled by SL2E
//   into qkb; K cols (1024..2047) into qkb; V cols -> vT [bh][d][T] b64-packed.
// ---------------------------------------------------------------------------
template<int MODE>
__global__ __launch_bounds__(256) void gemm_bt_kernel(
    const unsigned short* __restrict__ A, const unsigned short* __restrict__ Bt,
    const float* __restrict__ bias, float* __restrict__ Cout,
    unsigned short* __restrict__ qkb, unsigned short* __restrict__ vT,
    int M, int N, int K)
{
  __shared__ unsigned short Al[128 * 64];
  __shared__ unsigned short Bl[128 * 64];

  const int tid  = threadIdx.x;
  const int lane = tid & 63;
  const int wave = tid >> 6;
  const int col  = lane & 15;
  const int quad = lane >> 4;
  const int wm   = (wave & 1) * 64;
  const int wn   = (wave >> 1) * 64;
  const int bm0  = blockIdx.y * 128;
  const int bn0  = blockIdx.x * 128;
  const int cx   = col & 7;

  f32x4 acc[4][4];
  #pragma unroll
  for (int t = 0; t < 4; ++t)
    #pragma unroll
    for (int u = 0; u < 4; ++u) acc[t][u] = (f32x4)0.f;

  for (int k0 = 0; k0 < K; k0 += 64) {
    __syncthreads();
    #pragma unroll
    for (int i = 0; i < 4; ++i) {
      int idx = i * 256 + tid;
      int row = idx >> 3;
      int gc  = (idx & 7) ^ (row & 7);
      glds16(A  + (size_t)(bm0 + row) * K + k0 + gc * 8, &Al[idx * 8]);
      glds16(Bt + (size_t)(bn0 + row) * K + k0 + gc * 8, &Bl[idx * 8]);
    }
    __syncthreads();

    #pragma unroll
    for (int s = 0; s < 2; ++s) {
      s8v af[4], bf[4];
      #pragma unroll
      for (int t = 0; t < 4; ++t) {
        int ar = wm + t * 16 + col;
        af[t] = *(const s8v*)&Al[ar * 64 + (((s * 4 + quad) ^ cx) * 8)];
        int br = wn + t * 16 + col;
        bf[t] = *(const s8v*)&Bl[br * 64 + (((s * 4 + quad) ^ cx) * 8)];
      }
      #pragma unroll
      for (int t = 0; t < 4; ++t)
        #pragma unroll
        for (int u = 0; u < 4; ++u)
          acc[t][u] = __builtin_amdgcn_mfma_f32_16x16x32_bf16(
              af[t], bf[u], acc[t][u], 0, 0, 0);
    }
  }

  float bv[4];
  #pragma unroll
  for (int u = 0; u < 4; ++u) bv[u] = bias[bn0 + wn + u * 16 + col];

  if (MODE == 1 && bn0 >= 2048) {
    // V epilogue: packed b64 stores into vT [bh][d][T]
    #pragma unroll
    for (int t = 0; t < 4; ++t) {
      int m_base = bm0 + wm + t * 16 + quad * 4;
      #pragma unroll
      for (int u = 0; u < 4; ++u) {
        int hd = (bn0 + wn + u * 16 + col) - 2048;       // h*64 + d
        size_t bh = (size_t)(bm0 >> 11) * 16 + (hd >> 6);
        ull pk = (ull)f2bf(acc[t][u][0] + bv[u])
               | ((ull)f2bf(acc[t][u][1] + bv[u]) << 16)
               | ((ull)f2bf(acc[t][u][2] + bv[u]) << 32)
               | ((ull)f2bf(acc[t][u][3] + bv[u]) << 48);
        *(ull*)(vT + (bh * 64 + (hd & 63)) * 2048 + (m_base & 2047)) = pk;
      }
    }
  } else {
    const float sc = (MODE == 1 && (bn0 + wn) < 1024) ? SL2E : 1.0f;  // Q pre-scale
    #pragma unroll
    for (int t = 0; t < 4; ++t) {
      #pragma unroll
      for (int r = 0; r < 4; ++r) {
        size_t m = bm0 + wm + t * 16 + quad * 4 + r;
        #pragma unroll
        for (int u = 0; u < 4; ++u) {
          int n = bn0 + wn + u * 16 + col;
          float v = acc[t][u][r] + bv[u];
          if (MODE == 0) Cout[m * N + n] = v;
          else           qkb[m * 2048 + n] = f2bf(v * sc);
        }
      }
    }
  }
}

// ---------------------------------------------------------------------------
// Merged prep: x cast (blocks 0..8191), W_qkv transpose (8192..11263),
// W_proj transpose (11264..12287).
// ---------------------------------------------------------------------------
static __device__ __forceinline__ void transpose_tile(
    const float* __restrict__ W, unsigned short* __restrict__ Wt,
    int K, int N, int n0, int k0)
{
  __shared__ float tile[32][33];
  const int tx = threadIdx.x & 31, ty = threadIdx.x >> 5;
  #pragma unroll
  for (int i = 0; i < 4; ++i)
    tile[ty + i * 8][tx] = W[(size_t)(k0 + ty + i * 8) * N + n0 + tx];
  __syncthreads();
  #pragma unroll
  for (int i = 0; i < 4; ++i)
    Wt[(size_t)(n0 + ty + i * 8) * K + k0 + tx] = f2bf(tile[tx][ty + i * 8]);
}

__global__ __launch_bounds__(256) void prep_kernel(
    const float* __restrict__ x, const float* __restrict__ W_qkv,
    const float* __restrict__ W_proj, ushort4* __restrict__ xb,
    unsigned short* __restrict__ wqt, unsigned short* __restrict__ wpt)
{
  const int bid = blockIdx.x;
  if (bid < 8192) {
    int i = bid * 256 + threadIdx.x;
    float4 v = ((const float4*)x)[i];
    ushort4 o;
    o.x = f2bf(v.x); o.y = f2bf(v.y); o.z = f2bf(v.z); o.w = f2bf(v.w);
    xb[i] = o;
  } else if (bid < 8192 + 3072) {
    int b2 = bid - 8192;                      // W_qkv [1024, 3072] -> wqt
    transpose_tile(W_qkv, wqt, 1024, 3072, (b2 % 96) * 32, (b2 / 96) * 32);
  } else {
    int b3 = bid - 11264;                     // W_proj [1024, 1024] -> wpt
    transpose_tile(W_proj, wpt, 1024, 1024, (b3 % 32) * 32, (b3 / 32) * 32);
  }
}

// ---------------------------------------------------------------------------
// bf16 MFMA flash causal attention — QT=256, 8 waves (512 thr), KT=64,
// async dbuf, fixed-max softmax, TRANSPOSED-S + k-interleaved K-row
// permutation (round-5 proven structure; P never touches LDS).
// This round: ONLY add T5 s_setprio(1) around the QK and PV MFMA clusters
// (zero register cost; m191 attn-positive). Everything else is round-5
// verbatim — round-6's KT=128 lambda restructure caused scratch demotion
// (rule #20: FETCH 604 MB, VGPR 64->52, 518 µs) and is abandoned.
// ---------------------------------------------------------------------------
__global__ __launch_bounds__(512, 4) void attn_mfma_kernel(
    const unsigned short* __restrict__ qk, const unsigned short* __restrict__ vT,
    unsigned short* __restrict__ y)
{
  __shared__ unsigned short Ks[2][64 * 64];   // 16 KB
  __shared__ unsigned short Vs[2][64 * 64];   // 16 KB   (total 32 KB)

  const int tid  = threadIdx.x;
  const int wave = tid >> 6;
  const int lane = tid & 63;
  const int col  = lane & 15;
  const int quad = lane >> 4;
  const int cx   = col & 7;

  const int bh = blockIdx.x;
  const int b = bh >> 4, h = bh & 15;
  // pair-balanced qblk order: y=0..3 -> 7,6,5,4 (dispatched first), y=4..7 -> 0,1,2,3
  const int yy = (int)blockIdx.y;
  const int qblk = (yy < 4) ? (7 - yy) : (yy - 4);
  const int q0 = qblk * 256;
  const int nk = 4 * qblk + 4;
  const int C2 = 2048;

  const unsigned short* qbase = qk + (size_t)b * SEQ_T * C2 + h * 64;
  const unsigned short* kbase = qbase + 1024;
  const unsigned short* vbase = vT + (size_t)bh * 64 * 2048;

  // Q fragments for both stripes (B-operand: rows of Q, pre-scaled by SL2E)
  s8v qf[2][2];
  #pragma unroll
  for (int s = 0; s < 2; ++s)
    #pragma unroll
    for (int c = 0; c < 2; ++c)
      qf[s][c] = *(const s8v*)(qbase +
          (size_t)(q0 + s * 128 + wave * 16 + col) * C2 + c * 32 + quad * 8);

  f32x4 acc[2][4];
  #pragma unroll
  for (int s = 0; s < 2; ++s)
    #pragma unroll
    for (int t = 0; t < 4; ++t) acc[s][t] = (f32x4)0.f;
  float lsum[2] = {0.f, 0.f};                // per-lane partial row sum, q=col

  // 512 threads: exactly one glds16 per thread per tile (K and V)
  // K uses sigma(row) = (row&7)^((row>>1)&4); V keeps (row&7)
  auto stage = [&](int kt, int bi) {
    const int k0 = kt * 64;
    int row = tid >> 3;
    int gk  = (tid & 7) ^ (row & 7) ^ ((row >> 1) & 4);
    int gv  = (tid & 7) ^ (row & 7);
    glds16(kbase + (size_t)(k0 + row) * C2 + gk * 8, &Ks[bi][tid * 8]);
    glds16(vbase + (size_t)row * 2048 + k0 + gv * 8, &Vs[bi][tid * 8]);
  };

  auto tile_body = [&](int kt, int bi) {
    const int k0 = kt * 64;

    // K fragments, k-interleaved row permutation (A-operand)
    s8v kf[4][2];
    const int pbase = (col >> 2) * 8 + (col & 3);
    #pragma unroll
    for (int t = 0; t < 4; ++t) {
      const int rowt = pbase + (t & 1) * 4 + (t >> 1) * 32;
      const int sx   = (rowt & 7) ^ ((rowt >> 1) & 4);
      #pragma unroll
      for (int c = 0; c < 2; ++c)
        kf[t][c] = *(const s8v*)&Ks[bi][rowt * 64 + (((c * 4 + quad) ^ sx) * 8)];
    }

    // pass 1: QK^T + softmax per stripe; P stays in registers (pf)
    s8v pf[2][2];
    bool live[2];
    #pragma unroll
    for (int s = 0; s < 2; ++s) {
      const int qs = q0 + s * 128 + wave * 16;
      live[s] = (k0 <= qs + 15);
      if (!live[s]) continue;

      f32x4 st[4];
      #pragma unroll
      for (int t = 0; t < 4; ++t) st[t] = (f32x4)0.f;
      __builtin_amdgcn_s_setprio(1);
      #pragma unroll
      for (int t = 0; t < 4; ++t)
        #pragma unroll
        for (int c = 0; c < 2; ++c)
          st[t] = __builtin_amdgcn_mfma_f32_16x16x32_bf16(kf[t][c], qf[s][c], st[t], 0, 0, 0);
      __builtin_amdgcn_s_setprio(0);

      // lane (col,quad) holds P[q=qs+col][k0 + 8*quad + r + 4*(t&1) + 32*(t>>1)]
      uint2 pw[4];
      const bool diag = (k0 + 63 > qs);       // wave-uniform
      if (!diag) {
        #pragma unroll
        for (int t = 0; t < 4; ++t) {
          float e0 = EXP2(st[t][0]);
          float e1 = EXP2(st[t][1]);
          float e2 = EXP2(st[t][2]);
          float e3 = EXP2(st[t][3]);
          lsum[s] += (e0 + e1) + (e2 + e3);
          pw[t].x = cvtpk_bf16(e0, e1);
          pw[t].y = cvtpk_bf16(e2, e3);
        }
      } else {
        const int qg = qs + col;
        #pragma unroll
        for (int t = 0; t < 4; ++t) {
          const int kt0 = k0 + 4 * (t & 1) + 32 * (t >> 1);
          if (kt0 > qs + 15) {                // chunk fully masked (uniform)
            pw[t].x = 0u; pw[t].y = 0u;
          } else {
            const int kq = kt0 + 8 * quad;
            float e[4];
            #pragma unroll
            for (int r = 0; r < 4; ++r) {
              float v = EXP2(st[t][r]);
              if (kq + r > qg) v = 0.f;
              e[r] = v;
            }
            lsum[s] += (e[0] + e[1]) + (e[2] + e[3]);
            pw[t].x = cvtpk_bf16(e[0], e[1]);
            pw[t].y = cvtpk_bf16(e[2], e[3]);
          }
        }
      }
      // pf[c] = P chunk k = c*32 + quad*8 + {0..7}  (all lane-local)
      #pragma unroll
      for (int c = 0; c < 2; ++c) {
        union { uint4 u; s8v v; } cc;
        cc.u.x = pw[2 * c].x;  cc.u.y = pw[2 * c].y;
        cc.u.z = pw[2 * c + 1].x;  cc.u.w = pw[2 * c + 1].y;
        pf[s][c] = cc.v;
      }
    }

    // pass 2: V^T fragments (B-operand, rows d = t*16+col), then O += P·V^T
    s8v vf[4][2];
    #pragma unroll
    for (int t = 0; t < 4; ++t)
      #pragma unroll
      for (int c = 0; c < 2; ++c)
        vf[t][c] = *(const s8v*)&Vs[bi][(t * 16 + col) * 64 + (((c * 4 + quad) ^ cx) * 8)];
    __builtin_amdgcn_s_setprio(1);
    #pragma unroll
    for (int s = 0; s < 2; ++s) {
      if (!live[s]) continue;
      #pragma unroll
      for (int t = 0; t < 4; ++t)
        #pragma unroll
        for (int c = 0; c < 2; ++c)
          acc[s][t] = __builtin_amdgcn_mfma_f32_16x16x32_bf16(pf[s][c], vf[t][c], acc[s][t], 0, 0, 0);
    }
    __builtin_amdgcn_s_setprio(0);
  };

  stage(0, 0);
  for (int kt = 0; kt < nk; kt += 2) {
    __syncthreads();                               // buf0 staged & visible
    if (kt + 1 < nk) stage(kt + 1, 1);             // prefetch overlaps compute
    tile_body(kt, 0);
    if (kt + 1 < nk) {
      __syncthreads();                             // buf1 staged & visible
      if (kt + 2 < nk) stage(kt + 2, 0);
      tile_body(kt + 1, 1);
    }
  }

  // epilogue: reduce row sums across quads, broadcast per q, write y (bf16)
  #pragma unroll
  for (int s = 0; s < 2; ++s) {
    float v = lsum[s];
    v += __shfl_xor(v, 16);
    v += __shfl_xor(v, 32);                        // full sum for q = qs+col
    #pragma unroll
    for (int r = 0; r < 4; ++r) {
      float inv = 1.0f / __shfl(v, quad * 4 + r);  // sum for q-local quad*4+r
      int q = q0 + s * 128 + wave * 16 + quad * 4 + r;
      unsigned short* yrow = y + (size_t)(b * SEQ_T + q) * D_MODEL + h * 64;
      #pragma unroll
      for (int t = 0; t < 4; ++t)
        yrow[t * 16 + col] = f2bf(acc[s][t][r] * inv);
    }
  }
}

// ---------------------------------------------------------------------------
extern "C" void kernel_launch(void* const* d_in, const int* in_sizes, int n_in,
                              void* d_out, int out_size, void* d_ws, size_t ws_size,
                              hipStream_t stream) {
  const float* x      = (const float*)d_in[0];
  const float* W_qkv  = (const float*)d_in[1];
  const float* b_qkv  = (const float*)d_in[2];
  const float* W_proj = (const float*)d_in[3];
  const float* b_proj = (const float*)d_in[4];
  float* out = (float*)d_out;

  const int M  = BATCH * SEQ_T;    // 8192
  const int C  = D_MODEL;          // 1024
  const int C3 = 3 * D_MODEL;      // 3072

  // workspace (bf16 = unsigned short), total ~88 MB
  unsigned short* xb  = (unsigned short*)d_ws;           // [M, C]      16 MB
  unsigned short* wqt = xb  + (size_t)M * C;             // [3C, C]      6 MB
  unsigned short* wpt = wqt + (size_t)C3 * C;            // [C, C]       2 MB
  unsigned short* qkb = wpt + (size_t)C * C;             // [M, 2C]     32 MB
  unsigned short* vTb = qkb + (size_t)M * 2 * C;         // [64,64,T]   16 MB
  unsigned short* yb  = vTb + (size_t)64 * 64 * SEQ_T;   // [M, C]      16 MB

  dim3 blk(256);

  // 0) merged prep: cast x, transpose-cast both weights
  prep_kernel<<<dim3(8192 + 3072 + 1024), blk, 0, stream>>>(
      x, W_qkv, W_proj, (ushort4*)xb, wqt, wpt);

  // 1) qkv GEMM: Q (pre-scaled), K -> qkb; V -> vTb transposed [bh][d][T]
  gemm_bt_kernel<1><<<dim3(C3 / 128, M / 128), blk, 0, stream>>>(
      xb, wqt, b_qkv, nullptr, qkb, vTb, M, C3, C);

  // 2) causal flash attention: QT=256, 512 thr, P in registers (no Ps LDS)
  attn_mfma_kernel<<<dim3(BATCH * N_HEADS, SEQ_T / 256), dim3(512), 0, stream>>>(
      qkb, vTb, yb);

  // 3) out = y @ W_proj + b_proj (fp32)
  gemm_bt_kernel<0><<<dim3(C / 128, M / 128), blk, 0, stream>>>(
      yb, wpt, b_proj, out, nullptr, nullptr, M, C, C);
}

// Round 9
// 234.441 us; speedup vs baseline: 2.9413x; 1.0265x over previous
//
#include <hip/hip_runtime.h>
#include <hip/hip_bf16.h>

// Problem constants (match reference)
#define D_MODEL 1024
#define N_HEADS 16
#define HEAD_DIM 64
#define SEQ_T 2048
#define BATCH 4

#define SL2E 0.18033688011f   // 0.125 * log2(e), baked into Q at GEMM epilogue

typedef short s8v  __attribute__((ext_vector_type(8)));   // 8 x bf16 bits
typedef float f32x4 __attribute__((ext_vector_type(4)));
typedef unsigned long long ull;

static __device__ __forceinline__ unsigned short f2bf(float f) {
  union { float f; unsigned int u; } v; v.f = f;
  unsigned int u = v.u;
  return (unsigned short)((u + 0x7FFF + ((u >> 16) & 1)) >> 16);  // RNE
}

// pack 2 f32 -> 2 bf16 in one instr (RNE); no builtin on gfx950, inline asm
static __device__ __forceinline__ unsigned int cvtpk_bf16(float lo, float hi) {
  unsigned int r;
  asm("v_cvt_pk_bf16_f32 %0, %1, %2" : "=v"(r) : "v"(lo), "v"(hi));
  return r;
}

#if __has_builtin(__builtin_amdgcn_exp2f)
#define EXP2(x) __builtin_amdgcn_exp2f(x)
#else
#define EXP2(x) exp2f(x)
#endif

// async global->LDS, 16B per lane; LDS dest = wave-uniform base + lane*16
static __device__ __forceinline__ void glds16(const void* g, void* l) {
  __builtin_amdgcn_global_load_lds(
      (const __attribute__((address_space(1))) void*)g,
      (__attribute__((address_space(3))) void*)l, 16, 0, 0);
}

// raw barrier (no compiler-inserted vmcnt(0) drain) + compiler memory fence
#define BARRIER() do { asm volatile("" ::: "memory"); \
                       __builtin_amdgcn_s_barrier();  \
                       asm volatile("" ::: "memory"); } while (0)

// ---------------------------------------------------------------------------
// bf16 MFMA GEMM (m97 structure, proven 67-72.6 µs QKV): C = A @ B + bias
//   MODE 0: fp32 out. MODE 1: QKV split — Q cols (<1024) pre-scaled by SL2E
//   into qkb; K cols (1024..2047) into qkb; V cols -> vT [bh][d][T] b64-packed.
// ---------------------------------------------------------------------------
template<int MODE>
__global__ __launch_bounds__(256) void gemm_bt_kernel(
    const unsigned short* __restrict__ A, const unsigned short* __restrict__ Bt,
    const float* __restrict__ bias, float* __restrict__ Cout,
    unsigned short* __restrict__ qkb, unsigned short* __restrict__ vT,
    int M, int N, int K)
{
  __shared__ unsigned short Al[128 * 64];
  __shared__ unsigned short Bl[128 * 64];

  const int tid  = threadIdx.x;
  const int lane = tid & 63;
  const int wave = tid >> 6;
  const int col  = lane & 15;
  const int quad = lane >> 4;
  const int wm   = (wave & 1) * 64;
  const int wn   = (wave >> 1) * 64;
  const int bm0  = blockIdx.y * 128;
  const int bn0  = blockIdx.x * 128;
  const int cx   = col & 7;

  f32x4 acc[4][4];
  #pragma unroll
  for (int t = 0; t < 4; ++t)
    #pragma unroll
    for (int u = 0; u < 4; ++u) acc[t][u] = (f32x4)0.f;

  for (int k0 = 0; k0 < K; k0 += 64) {
    __syncthreads();
    #pragma unroll
    for (int i = 0; i < 4; ++i) {
      int idx = i * 256 + tid;
      int row = idx >> 3;
      int gc  = (idx & 7) ^ (row & 7);
      glds16(A  + (size_t)(bm0 + row) * K + k0 + gc * 8, &Al[idx * 8]);
      glds16(Bt + (size_t)(bn0 + row) * K + k0 + gc * 8, &Bl[idx * 8]);
    }
    __syncthreads();

    #pragma unroll
    for (int s = 0; s < 2; ++s) {
      s8v af[4], bf[4];
      #pragma unroll
      for (int t = 0; t < 4; ++t) {
        int ar = wm + t * 16 + col;
        af[t] = *(const s8v*)&Al[ar * 64 + (((s * 4 + quad) ^ cx) * 8)];
        int br = wn + t * 16 + col;
        bf[t] = *(const s8v*)&Bl[br * 64 + (((s * 4 + quad) ^ cx) * 8)];
      }
      #pragma unroll
      for (int t = 0; t < 4; ++t)
        #pragma unroll
        for (int u = 0; u < 4; ++u)
          acc[t][u] = __builtin_amdgcn_mfma_f32_16x16x32_bf16(
              af[t], bf[u], acc[t][u], 0, 0, 0);
    }
  }

  float bv[4];
  #pragma unroll
  for (int u = 0; u < 4; ++u) bv[u] = bias[bn0 + wn + u * 16 + col];

  if (MODE == 1 && bn0 >= 2048) {
    // V epilogue: packed b64 stores into vT [bh][d][T]
    #pragma unroll
    for (int t = 0; t < 4; ++t) {
      int m_base = bm0 + wm + t * 16 + quad * 4;
      #pragma unroll
      for (int u = 0; u < 4; ++u) {
        int hd = (bn0 + wn + u * 16 + col) - 2048;       // h*64 + d
        size_t bh = (size_t)(bm0 >> 11) * 16 + (hd >> 6);
        ull pk = (ull)f2bf(acc[t][u][0] + bv[u])
               | ((ull)f2bf(acc[t][u][1] + bv[u]) << 16)
               | ((ull)f2bf(acc[t][u][2] + bv[u]) << 32)
               | ((ull)f2bf(acc[t][u][3] + bv[u]) << 48);
        *(ull*)(vT + (bh * 64 + (hd & 63)) * 2048 + (m_base & 2047)) = pk;
      }
    }
  } else {
    const float sc = (MODE == 1 && (bn0 + wn) < 1024) ? SL2E : 1.0f;  // Q pre-scale
    #pragma unroll
    for (int t = 0; t < 4; ++t) {
      #pragma unroll
      for (int r = 0; r < 4; ++r) {
        size_t m = bm0 + wm + t * 16 + quad * 4 + r;
        #pragma unroll
        for (int u = 0; u < 4; ++u) {
          int n = bn0 + wn + u * 16 + col;
          float v = acc[t][u][r] + bv[u];
          if (MODE == 0) Cout[m * N + n] = v;
          else           qkb[m * 2048 + n] = f2bf(v * sc);
        }
      }
    }
  }
}

// ---------------------------------------------------------------------------
// Merged prep: x cast (blocks 0..8191), W_qkv transpose (8192..11263),
// W_proj transpose (11264..12287).
// ---------------------------------------------------------------------------
static __device__ __forceinline__ void transpose_tile(
    const float* __restrict__ W, unsigned short* __restrict__ Wt,
    int K, int N, int n0, int k0)
{
  __shared__ float tile[32][33];
  const int tx = threadIdx.x & 31, ty = threadIdx.x >> 5;
  #pragma unroll
  for (int i = 0; i < 4; ++i)
    tile[ty + i * 8][tx] = W[(size_t)(k0 + ty + i * 8) * N + n0 + tx];
  __syncthreads();
  #pragma unroll
  for (int i = 0; i < 4; ++i)
    Wt[(size_t)(n0 + ty + i * 8) * K + k0 + tx] = f2bf(tile[tx][ty + i * 8]);
}

__global__ __launch_bounds__(256) void prep_kernel(
    const float* __restrict__ x, const float* __restrict__ W_qkv,
    const float* __restrict__ W_proj, ushort4* __restrict__ xb,
    unsigned short* __restrict__ wqt, unsigned short* __restrict__ wpt)
{
  const int bid = blockIdx.x;
  if (bid < 8192) {
    int i = bid * 256 + threadIdx.x;
    float4 v = ((const float4*)x)[i];
    ushort4 o;
    o.x = f2bf(v.x); o.y = f2bf(v.y); o.z = f2bf(v.z); o.w = f2bf(v.w);
    xb[i] = o;
  } else if (bid < 8192 + 3072) {
    int b2 = bid - 8192;                      // W_qkv [1024, 3072] -> wqt
    transpose_tile(W_qkv, wqt, 1024, 3072, (b2 % 96) * 32, (b2 / 96) * 32);
  } else {
    int b3 = bid - 11264;                     // W_proj [1024, 1024] -> wpt
    transpose_tile(W_proj, wpt, 1024, 1024, (b3 % 32) * 32, (b3 / 32) * 32);
  }
}

// ---------------------------------------------------------------------------
// bf16 MFMA flash causal attention — QT=256, 8 waves (512 thr), KT=64,
// fixed-max softmax, TRANSPOSED-S + k-interleaved K-row permutation
// (round-5 proven structure; P never touches LDS).
// This round: 2-deep dbuf -> 3-DEEP ROTATING K/V BUFFERS with counted
// vmcnt (T4 applied to attn staging). Per tile: vmcnt(2) drains exactly
// stage(kt) (keeps stage(kt+1)'s 2 loads in flight), raw barrier, issue
// stage(kt+2), body(kt). Prefetch distance ~2 bodies >> HBM/L3 latency,
// and the loop never drains vmcnt to 0 (tail only). Race-freedom:
// stage(kt+2) targets buf (kt+2)%3 = (kt-1)%3 whose last reader finished
// before this iteration's barrier; in-flight stages hit distinct buffers.
// LDS 48 KB -> still 2 blocks/CU. Register structure unchanged.
// ---------------------------------------------------------------------------
__global__ __launch_bounds__(512, 4) void attn_mfma_kernel(
    const unsigned short* __restrict__ qk, const unsigned short* __restrict__ vT,
    unsigned short* __restrict__ y)
{
  __shared__ unsigned short Ks[3][64 * 64];   // 24 KB
  __shared__ unsigned short Vs[3][64 * 64];   // 24 KB   (total 48 KB)

  const int tid  = threadIdx.x;
  const int wave = tid >> 6;
  const int lane = tid & 63;
  const int col  = lane & 15;
  const int quad = lane >> 4;
  const int cx   = col & 7;

  const int bh = blockIdx.x;
  const int b = bh >> 4, h = bh & 15;
  // pair-balanced qblk order: y=0..3 -> 7,6,5,4 (dispatched first), y=4..7 -> 0,1,2,3
  const int yy = (int)blockIdx.y;
  const int qblk = (yy < 4) ? (7 - yy) : (yy - 4);
  const int q0 = qblk * 256;
  const int nk = 4 * qblk + 4;               // always >= 4
  const int C2 = 2048;

  const unsigned short* qbase = qk + (size_t)b * SEQ_T * C2 + h * 64;
  const unsigned short* kbase = qbase + 1024;
  const unsigned short* vbase = vT + (size_t)bh * 64 * 2048;

  // Q fragments for both stripes (B-operand: rows of Q, pre-scaled by SL2E)
  s8v qf[2][2];
  #pragma unroll
  for (int s = 0; s < 2; ++s)
    #pragma unroll
    for (int c = 0; c < 2; ++c)
      qf[s][c] = *(const s8v*)(qbase +
          (size_t)(q0 + s * 128 + wave * 16 + col) * C2 + c * 32 + quad * 8);

  f32x4 acc[2][4];
  #pragma unroll
  for (int s = 0; s < 2; ++s)
    #pragma unroll
    for (int t = 0; t < 4; ++t) acc[s][t] = (f32x4)0.f;
  float lsum[2] = {0.f, 0.f};                // per-lane partial row sum, q=col

  // 512 threads: exactly one glds16 per thread per tile (K and V) = 2 vmem/wave
  // K uses sigma(row) = (row&7)^((row>>1)&4); V keeps (row&7)
  auto stage = [&](int kt, int bi) {
    const int k0 = kt * 64;
    int row = tid >> 3;
    int gk  = (tid & 7) ^ (row & 7) ^ ((row >> 1) & 4);
    int gv  = (tid & 7) ^ (row & 7);
    glds16(kbase + (size_t)(k0 + row) * C2 + gk * 8, &Ks[bi][tid * 8]);
    glds16(vbase + (size_t)row * 2048 + k0 + gv * 8, &Vs[bi][tid * 8]);
  };

  auto tile_body = [&](int kt, int bi) {
    const int k0 = kt * 64;

    // K fragments, k-interleaved row permutation (A-operand)
    s8v kf[4][2];
    const int pbase = (col >> 2) * 8 + (col & 3);
    #pragma unroll
    for (int t = 0; t < 4; ++t) {
      const int rowt = pbase + (t & 1) * 4 + (t >> 1) * 32;
      const int sx   = (rowt & 7) ^ ((rowt >> 1) & 4);
      #pragma unroll
      for (int c = 0; c < 2; ++c)
        kf[t][c] = *(const s8v*)&Ks[bi][rowt * 64 + (((c * 4 + quad) ^ sx) * 8)];
    }

    // pass 1: QK^T + softmax per stripe; P stays in registers (pf)
    s8v pf[2][2];
    bool live[2];
    #pragma unroll
    for (int s = 0; s < 2; ++s) {
      const int qs = q0 + s * 128 + wave * 16;
      live[s] = (k0 <= qs + 15);
      if (!live[s]) continue;

      f32x4 st[4];
      #pragma unroll
      for (int t = 0; t < 4; ++t) st[t] = (f32x4)0.f;
      __builtin_amdgcn_s_setprio(1);
      #pragma unroll
      for (int t = 0; t < 4; ++t)
        #pragma unroll
        for (int c = 0; c < 2; ++c)
          st[t] = __builtin_amdgcn_mfma_f32_16x16x32_bf16(kf[t][c], qf[s][c], st[t], 0, 0, 0);
      __builtin_amdgcn_s_setprio(0);

      // lane (col,quad) holds P[q=qs+col][k0 + 8*quad + r + 4*(t&1) + 32*(t>>1)]
      uint2 pw[4];
      const bool diag = (k0 + 63 > qs);       // wave-uniform
      if (!diag) {
        #pragma unroll
        for (int t = 0; t < 4; ++t) {
          float e0 = EXP2(st[t][0]);
          float e1 = EXP2(st[t][1]);
          float e2 = EXP2(st[t][2]);
          float e3 = EXP2(st[t][3]);
          lsum[s] += (e0 + e1) + (e2 + e3);
          pw[t].x = cvtpk_bf16(e0, e1);
          pw[t].y = cvtpk_bf16(e2, e3);
        }
      } else {
        const int qg = qs + col;
        #pragma unroll
        for (int t = 0; t < 4; ++t) {
          const int kt0 = k0 + 4 * (t & 1) + 32 * (t >> 1);
          if (kt0 > qs + 15) {                // chunk fully masked (uniform)
            pw[t].x = 0u; pw[t].y = 0u;
          } else {
            const int kq = kt0 + 8 * quad;
            float e[4];
            #pragma unroll
            for (int r = 0; r < 4; ++r) {
              float v = EXP2(st[t][r]);
              if (kq + r > qg) v = 0.f;
              e[r] = v;
            }
            lsum[s] += (e[0] + e[1]) + (e[2] + e[3]);
            pw[t].x = cvtpk_bf16(e[0], e[1]);
            pw[t].y = cvtpk_bf16(e[2], e[3]);
          }
        }
      }
      // pf[c] = P chunk k = c*32 + quad*8 + {0..7}  (all lane-local)
      #pragma unroll
      for (int c = 0; c < 2; ++c) {
        union { uint4 u; s8v v; } cc;
        cc.u.x = pw[2 * c].x;  cc.u.y = pw[2 * c].y;
        cc.u.z = pw[2 * c + 1].x;  cc.u.w = pw[2 * c + 1].y;
        pf[s][c] = cc.v;
      }
    }

    // pass 2: V^T fragments (B-operand, rows d = t*16+col), then O += P·V^T
    s8v vf[4][2];
    #pragma unroll
    for (int t = 0; t < 4; ++t)
      #pragma unroll
      for (int c = 0; c < 2; ++c)
        vf[t][c] = *(const s8v*)&Vs[bi][(t * 16 + col) * 64 + (((c * 4 + quad) ^ cx) * 8)];
    __builtin_amdgcn_s_setprio(1);
    #pragma unroll
    for (int s = 0; s < 2; ++s) {
      if (!live[s]) continue;
      #pragma unroll
      for (int t = 0; t < 4; ++t)
        #pragma unroll
        for (int c = 0; c < 2; ++c)
          acc[s][t] = __builtin_amdgcn_mfma_f32_16x16x32_bf16(pf[s][c], vf[t][c], acc[s][t], 0, 0, 0);
    }
    __builtin_amdgcn_s_setprio(0);
  };

  // 3-deep rotating pipeline, counted vmcnt (2 vmem per stage per wave):
  // invariant at loop top: outstanding = stage(kt) + stage(kt+1) = 4 ops;
  // vmcnt(2) drains exactly stage(kt). Last tile drains to 0.
  stage(0, 0);
  stage(1, 1);
  for (int kt = 0; kt < nk; ++kt) {
    const int bi = kt % 3;
    if (kt + 1 < nk) asm volatile("s_waitcnt vmcnt(2)" ::: "memory");
    else             asm volatile("s_waitcnt vmcnt(0)" ::: "memory");
    BARRIER();                                   // buf bi staged & visible;
                                                 // all waves done with body(kt-1)
    if (kt + 2 < nk) stage(kt + 2, (kt + 2) % 3);  // overwrites buf (kt-1)%3
    tile_body(kt, bi);
  }

  // epilogue: reduce row sums across quads, broadcast per q, write y (bf16)
  #pragma unroll
  for (int s = 0; s < 2; ++s) {
    float v = lsum[s];
    v += __shfl_xor(v, 16);
    v += __shfl_xor(v, 32);                        // full sum for q = qs+col
    #pragma unroll
    for (int r = 0; r < 4; ++r) {
      float inv = 1.0f / __shfl(v, quad * 4 + r);  // sum for q-local quad*4+r
      int q = q0 + s * 128 + wave * 16 + quad * 4 + r;
      unsigned short* yrow = y + (size_t)(b * SEQ_T + q) * D_MODEL + h * 64;
      #pragma unroll
      for (int t = 0; t < 4; ++t)
        yrow[t * 16 + col] = f2bf(acc[s][t][r] * inv);
    }
  }
}

// ---------------------------------------------------------------------------
extern "C" void kernel_launch(void* const* d_in, const int* in_sizes, int n_in,
                              void* d_out, int out_size, void* d_ws, size_t ws_size,
                              hipStream_t stream) {
  const float* x      = (const float*)d_in[0];
  const float* W_qkv  = (const float*)d_in[1];
  const float* b_qkv  = (const float*)d_in[2];
  const float* W_proj = (const float*)d_in[3];
  const float* b_proj = (const float*)d_in[4];
  float* out = (float*)d_out;

  const int M  = BATCH * SEQ_T;    // 8192
  const int C  = D_MODEL;          // 1024
  const int C3 = 3 * D_MODEL;      // 3072

  // workspace (bf16 = unsigned short), total ~88 MB
  unsigned short* xb  = (unsigned short*)d_ws;           // [M, C]      16 MB
  unsigned short* wqt = xb  + (size_t)M * C;             // [3C, C]      6 MB
  unsigned short* wpt = wqt + (size_t)C3 * C;            // [C, C]       2 MB
  unsigned short* qkb = wpt + (size_t)C * C;             // [M, 2C]     32 MB
  unsigned short* vTb = qkb + (size_t)M * 2 * C;         // [64,64,T]   16 MB
  unsigned short* yb  = vTb + (size_t)64 * 64 * SEQ_T;   // [M, C]      16 MB

  dim3 blk(256);

  // 0) merged prep: cast x, transpose-cast both weights
  prep_kernel<<<dim3(8192 + 3072 + 1024), blk, 0, stream>>>(
      x, W_qkv, W_proj, (ushort4*)xb, wqt, wpt);

  // 1) qkv GEMM: Q (pre-scaled), K -> qkb; V -> vTb transposed [bh][d][T]
  gemm_bt_kernel<1><<<dim3(C3 / 128, M / 128), blk, 0, stream>>>(
      xb, wqt, b_qkv, nullptr, qkb, vTb, M, C3, C);

  // 2) causal flash attention: QT=256, 512 thr, 3-deep counted-vmcnt staging
  attn_mfma_kernel<<<dim3(BATCH * N_HEADS, SEQ_T / 256), dim3(512), 0, stream>>>(
      qkb, vTb, yb);

  // 3) out = y @ W_proj + b_proj (fp32)
  gemm_bt_kernel<0><<<dim3(C / 128, M / 128), blk, 0, stream>>>(
      yb, wpt, b_proj, out, nullptr, nullptr, M, C, C);
}